// Round 8
// baseline (93.526 us; speedup 1.0000x reference)
//
#include <hip/hip_runtime.h>
#include <cstdint>
#include <math.h>

#define BATCH 32
#define NPIX (512*512)        // 262144 pixels per batch
#define NB1 1024              // level-1 bins: tp bits [31:22]
#define NCOPY 4               // LDS sub-histogram copies
#define NBA 2048              // select level A: tp bits [21:11]
#define NBB 2048              // select level B: tp bits [10:0]
#define PXB 4096              // pixels per block (256 thr * 16 px)
#define FGCAP 131072          // fg-list capacity per batch (32 MB total)
#define CAP 131072            // candidate capacity per batch (32 MB total)
#define CAP2 32768            // binA-candidate capacity per batch (8 MB total)
#define CNTSTRIDE 32          // one cache line (128B) per batch counter

struct State {
    int      pfx1[BATCH];            // selected 10-bit prefix (-1 if no fg)
    uint32_t krem[BATCH];            // rank within pfx1 bin (1-based)
    int      binA[BATCH];            // selected level-A bin
    uint32_t remA[BATCH];            // rank within binA (1-based)
    uint32_t fgcnt  [BATCH*CNTSTRIDE];  // fg-list count, line-padded
    uint32_t candcnt[BATCH*CNTSTRIDE];  // candidate count, line-padded
    uint32_t cnt2   [BATCH*CNTSTRIDE];  // binA-candidate count, line-padded
    double   I_low[BATCH];           // sum p     over surely-kept fg
    double   U_low[BATCH];           // sum p^2+1 over same
    double   S_bg [BATCH];           // sum p^2 over background
    double   I_cnd[BATCH];           // sum p     over kept candidates
    double   U_cnd[BATCH];           // sum p^2+1 over kept candidates
};

// ---------------------------------------------------------------------------
// Pass 1: softmax; S_bg inline; fg pixels -> compact list {tp_bits, p_bits};
// LDS level-1 histogram of tp bits. launch_bounds(256,2): allow big VGPR
// budget so all 16 float4 loads stay in flight (R7 was latency-bound at
// VGPR=40 with ~4 loads outstanding).
// ---------------------------------------------------------------------------
__global__ __launch_bounds__(256, 2)
void k_pass1(const float* __restrict__ logits,
             const float* __restrict__ target,
             const float* __restrict__ eps,
             uint2* __restrict__ fgList,
             uint32_t* __restrict__ hist1,
             State* st)
{
    __shared__ uint32_t lh[NB1 * NCOPY];   // 16 KB
    const int tid = threadIdx.x;
    const int lane = tid & 63;
    const int copy = tid & (NCOPY - 1);
    for (int i = tid; i < NB1 * NCOPY; i += 256) lh[i] = 0;
    __syncthreads();

    const int b = blockIdx.y;
    const size_t nbase = (size_t)b * NPIX;
    const size_t lbase = (size_t)b * 2 * NPIX;
    const int base = blockIdx.x * PXB;
    uint2* fgb = fgList + (size_t)b * FGCAP;

    float4 L0[4], L1[4], T4[4], E4[4];
#pragma unroll
    for (int it = 0; it < 4; ++it) {
        const int i0 = base + (it * 256 + tid) * 4;
        L0[it] = *(const float4*)(logits + lbase + i0);
        L1[it] = *(const float4*)(logits + lbase + NPIX + i0);
        T4[it] = *(const float4*)(target + nbase + i0);
        E4[it] = *(const float4*)(eps    + nbase + i0);
    }

    uint32_t tpb_[16], pb_[16];
    uint32_t predmask = 0;
    double Sbg = 0.0;
#pragma unroll
    for (int it = 0; it < 4; ++it) {
        float a0[4] = {L0[it].x, L0[it].y, L0[it].z, L0[it].w};
        float a1[4] = {L1[it].x, L1[it].y, L1[it].z, L1[it].w};
        float tv[4] = {T4[it].x, T4[it].y, T4[it].z, T4[it].w};
        float ev[4] = {E4[it].x, E4[it].y, E4[it].z, E4[it].w};
#pragma unroll
        for (int j = 0; j < 4; ++j) {
            const int idx = it * 4 + j;
            float m  = fmaxf(a0[j], a1[j]);
            float e0 = expf(a0[j] - m);
            float e1 = expf(a1[j] - m);
            float p  = e1 / (e0 + e1);
            float tp = p * (tv[j] + ev[j]);
            bool fg  = (tv[j] == 1.0f);
            if (fg) {
                uint32_t bits = __float_as_uint(tp);
                atomicAdd(&lh[(bits >> 22) * NCOPY + copy], 1u);
                predmask |= (1u << idx);
                tpb_[idx] = bits;
                pb_[idx]  = __float_as_uint(p);
            } else {
                Sbg += (double)p * (double)p;
                tpb_[idx] = 0; pb_[idx] = 0;
            }
        }
    }

    // Wave-aggregated append to fg list: ONE returning atomic per wave.
    uint32_t c = (uint32_t)__popc(predmask);
    uint32_t inc = c;
#pragma unroll
    for (int off = 1; off < 64; off <<= 1) {
        uint32_t v = __shfl_up(inc, off);
        if (lane >= off) inc += v;
    }
    uint32_t excl = inc - c;
    uint32_t wtotal = __shfl(inc, 63);
    uint32_t basec = 0;
    if (lane == 0 && wtotal) basec = atomicAdd(&st->fgcnt[b * CNTSTRIDE], wtotal);
    basec = __shfl(basec, 0);

    uint32_t pos = basec + excl;
#pragma unroll
    for (int idx = 0; idx < 16; ++idx) {
        if ((predmask >> idx) & 1u) {
            if (pos < FGCAP) fgb[pos] = make_uint2(tpb_[idx], pb_[idx]);
            pos++;
        }
    }

    __syncthreads();
    uint32_t* hb = hist1 + (size_t)b * NB1;
    for (int bin = tid; bin < NB1; bin += 256) {
        uint32_t v = lh[bin*NCOPY+0] + lh[bin*NCOPY+1] + lh[bin*NCOPY+2] + lh[bin*NCOPY+3];
        if (v) atomicAdd(hb + bin, v);
    }

    __shared__ double sB[256];
    sB[tid] = Sbg;
    __syncthreads();
    for (int off = 128; off > 0; off >>= 1) {
        if (tid < off) sB[tid] += sB[tid + off];
        __syncthreads();
    }
    if (tid == 0) atomicAdd(&st->S_bg[b], sB[0]);
}

// ---------------------------------------------------------------------------
// Scan level-1: pick 10-bit prefix containing rank k = max(1, n_fg/2).
// ---------------------------------------------------------------------------
__global__ __launch_bounds__(256)
void k_scan1(const uint32_t* __restrict__ hist1, State* st)
{
    const int b = blockIdx.x;
    const int t = threadIdx.x;
    const uint32_t* h = hist1 + (size_t)b * NB1;
    __shared__ uint32_t part[256];
    __shared__ int sBin; __shared__ uint32_t sRem;
    if (t == 0) { sBin = 0; sRem = 1; }

    const int g = NB1 / 256;   // 4
    uint32_t s = 0;
    for (int j = 0; j < g; ++j) s += h[t * g + j];
    part[t] = s;
    __syncthreads();
    for (int off = 1; off < 256; off <<= 1) {
        uint32_t v = (t >= off) ? part[t - off] : 0u;
        __syncthreads();
        part[t] += v;
        __syncthreads();
    }
    uint32_t incl = part[t], excl = incl - s;
    uint32_t total = part[255];
    if (total == 0) {
        if (t == 0) { st->pfx1[b] = -1; st->krem[b] = 0; }
        return;
    }
    uint32_t k = total / 2;
    if (k == 0) k = 1;

    if (excl < k && k <= incl) {
        uint32_t run = excl;
        for (int j = 0; j < g; ++j) {
            uint32_t c = h[t * g + j];
            if (run < k && k <= run + c) { sBin = t * g + j; sRem = k - run; break; }
            run += c;
        }
    }
    __syncthreads();
    if (t == 0) { st->pfx1[b] = sBin; st->krem[b] = sRem; }
}

// ---------------------------------------------------------------------------
// Sums pass over the fg list: bin<pfx1 -> I/U_low; bin==pfx1 -> candidate
// (append + LDS level-A histogram).
// ---------------------------------------------------------------------------
__global__ __launch_bounds__(256)
void k_sums(const uint2* __restrict__ fgList,
            State* st, uint2* __restrict__ cand,
            uint32_t* __restrict__ histA)
{
    const int b = blockIdx.y;
    const int t = threadIdx.x;
    const int lane = t & 63;
    const int pfx = st->pfx1[b];
    if (pfx < 0) return;
    const uint32_t n = min(st->fgcnt[b * CNTSTRIDE], (uint32_t)FGCAP);
    const uint2* fgb = fgList + (size_t)b * FGCAP;
    uint2* cb = cand + (size_t)b * CAP;

    __shared__ uint32_t lhA[NBA];          // 8 KB
    for (int i = t; i < NBA; i += 256) lhA[i] = 0;
    __syncthreads();

    double I = 0.0, U = 0.0;
    for (uint32_t i = blockIdx.x * 256 + t; i < n; i += gridDim.x * 256) {
        uint2 e = fgb[i];
        uint32_t pf = e.x >> 22;
        if ((int)pf < pfx) {
            float p = __uint_as_float(e.y);
            I += (double)p;
            U += (double)p * (double)p + 1.0;
        }
        bool isc = ((int)pf == pfx);
        if (isc) atomicAdd(&lhA[(e.x >> 11) & (NBA - 1)], 1u);
        unsigned long long msk = __ballot(isc);
        if (msk) {
            int leader = __ffsll((long long)msk) - 1;
            uint32_t cnt = (uint32_t)__popcll(msk);
            uint32_t basec = 0;
            if (lane == leader) basec = atomicAdd(&st->candcnt[b * CNTSTRIDE], cnt);
            basec = __shfl(basec, leader);
            if (isc) {
                uint32_t off = (uint32_t)__popcll(msk & ((1ULL << lane) - 1ULL));
                uint32_t pos = basec + off;
                if (pos < CAP) cb[pos] = e;
            }
        }
    }

    __syncthreads();
    uint32_t* hA = histA + (size_t)b * NBA;
    for (int i = t; i < NBA; i += 256) {
        uint32_t v = lhA[i];
        if (v) atomicAdd(hA + i, v);
    }

    __shared__ double sI[256];
    __shared__ double sU[256];
    sI[t] = I; sU[t] = U;
    __syncthreads();
    for (int off = 128; off > 0; off >>= 1) {
        if (t < off) { sI[t] += sI[t+off]; sU[t] += sU[t+off]; }
        __syncthreads();
    }
    if (t == 0) {
        atomicAdd(&st->I_low[b], sI[0]);
        atomicAdd(&st->U_low[b], sU[0]);
    }
}

// ---------------------------------------------------------------------------
#define SELECT_BIN(h, nb, k)                                                  \
    {                                                                         \
        const int g = (nb) / 256;                                             \
        uint32_t s = 0;                                                       \
        for (int j = 0; j < g; ++j) s += (h)[t * g + j];                      \
        part[t] = s;                                                          \
        __syncthreads();                                                      \
        for (int off = 1; off < 256; off <<= 1) {                             \
            uint32_t v = (t >= off) ? part[t - off] : 0u;                     \
            __syncthreads();                                                  \
            part[t] += v;                                                     \
            __syncthreads();                                                  \
        }                                                                     \
        uint32_t incl = part[t], excl = incl - s;                             \
        if (excl < (k) && (k) <= incl) {                                      \
            uint32_t run = excl;                                              \
            for (int j = 0; j < g; ++j) {                                     \
                uint32_t c = (h)[t * g + j];                                  \
                if (run < (k) && (k) <= run + c) {                            \
                    sBin = t * g + j;                                         \
                    sRem = (k) - run;                                         \
                    break;                                                    \
                }                                                             \
                run += c;                                                     \
            }                                                                 \
        }                                                                     \
        __syncthreads();                                                      \
    }

// Scan level-A histogram -> binA, remA. One small block per batch.
__global__ __launch_bounds__(256)
void k_scanA(const uint32_t* __restrict__ histA, State* st)
{
    const int b = blockIdx.x;
    const int t = threadIdx.x;
    if (st->pfx1[b] < 0) return;
    const uint32_t* h = histA + (size_t)b * NBA;
    const uint32_t k = st->krem[b];
    __shared__ uint32_t part[256];
    __shared__ int sBin; __shared__ uint32_t sRem;
    if (t == 0) { sBin = 0; sRem = 1; }
    __syncthreads();
    SELECT_BIN(h, NBA, k);
    if (t == 0) { st->binA[b] = sBin; st->remA[b] = sRem; }
}

// ---------------------------------------------------------------------------
// Level-B pass over candidates (parallel): sub<binA -> kept sums; sub==binA ->
// LDS histB + compact into tiny cand2 list.
// ---------------------------------------------------------------------------
__global__ __launch_bounds__(256)
void k_histB(State* st, const uint2* __restrict__ cand,
             uint32_t* __restrict__ histB, uint2* __restrict__ cand2)
{
    const int b = blockIdx.y;
    const int t = threadIdx.x;
    if (st->pfx1[b] < 0) return;
    const uint32_t binA = (uint32_t)st->binA[b];
    const uint32_t n = min(st->candcnt[b * CNTSTRIDE], (uint32_t)CAP);
    const uint2* cb = cand + (size_t)b * CAP;
    uint2* c2 = cand2 + (size_t)b * CAP2;

    __shared__ uint32_t lhB[NBB];          // 8 KB
    for (int i = t; i < NBB; i += 256) lhB[i] = 0;
    __syncthreads();

    double I = 0.0, U = 0.0;
    for (uint32_t i = blockIdx.x * 256 + t; i < n; i += gridDim.x * 256) {
        uint2 cv = cb[i];
        uint32_t sub = (cv.x >> 11) & (NBA - 1);
        if (sub < binA) {
            float p = __uint_as_float(cv.y);
            I += (double)p;
            U += (double)p * (double)p + 1.0;
        } else if (sub == binA) {
            atomicAdd(&lhB[cv.x & (NBB - 1)], 1u);
            uint32_t pos = atomicAdd(&st->cnt2[b * CNTSTRIDE], 1u);
            if (pos < CAP2) c2[pos] = cv;
        }
    }

    __syncthreads();
    uint32_t* hB = histB + (size_t)b * NBB;
    for (int i = t; i < NBB; i += 256) {
        uint32_t v = lhB[i];
        if (v) atomicAdd(hB + i, v);
    }

    __shared__ double sI[256];
    __shared__ double sU[256];
    sI[t] = I; sU[t] = U;
    __syncthreads();
    for (int off = 128; off > 0; off >>= 1) {
        if (t < off) { sI[t] += sI[t+off]; sU[t] += sU[t+off]; }
        __syncthreads();
    }
    if (t == 0) {
        atomicAdd(&st->I_cnd[b], sI[0]);
        atomicAdd(&st->U_cnd[b], sU[0]);
    }
}

// ---------------------------------------------------------------------------
// Scan level-B histogram -> binB -> thr; sum the tiny cand2 list <= thr.
// ---------------------------------------------------------------------------
__global__ __launch_bounds__(256)
void k_scanB(State* st, const uint32_t* __restrict__ histB,
             const uint2* __restrict__ cand2)
{
    const int b = blockIdx.x;
    const int t = threadIdx.x;
    const int pfx = st->pfx1[b];
    if (pfx < 0) return;
    const uint32_t* h = histB + (size_t)b * NBB;
    const uint32_t k = st->remA[b];
    const uint32_t binA = (uint32_t)st->binA[b];
    const uint2* c2 = cand2 + (size_t)b * CAP2;
    const uint32_t n2 = min(st->cnt2[b * CNTSTRIDE], (uint32_t)CAP2);

    __shared__ uint32_t part[256];
    __shared__ int sBin; __shared__ uint32_t sRem;
    if (t == 0) { sBin = 0; sRem = 1; }
    __syncthreads();
    SELECT_BIN(h, NBB, k);
    const uint32_t binB = (uint32_t)sBin;
    const uint32_t thr_bits = ((uint32_t)pfx << 22) | (binA << 11) | binB;

    double I = 0.0, U = 0.0;
    for (uint32_t i = t; i < n2; i += 256) {
        uint2 cv = c2[i];
        if (cv.x <= thr_bits) {
            float p = __uint_as_float(cv.y);
            I += (double)p;
            U += (double)p * (double)p + 1.0;
        }
    }
    __shared__ double sI[256];
    __shared__ double sU[256];
    sI[t] = I; sU[t] = U;
    __syncthreads();
    for (int off = 128; off > 0; off >>= 1) {
        if (t < off) { sI[t] += sI[t+off]; sU[t] += sU[t+off]; }
        __syncthreads();
    }
    if (t == 0) {
        atomicAdd(&st->I_cnd[b], sI[0]);
        atomicAdd(&st->U_cnd[b], sU[0]);
    }
}

__global__ void k_finalize(const State* __restrict__ st, float* __restrict__ out)
{
    const int t = threadIdx.x;
    double d = 0.0;
    if (t < BATCH) {
        double I = st->I_low[t] + st->I_cnd[t];
        double U = st->U_low[t] + st->U_cnd[t] + st->S_bg[t];
        d = (2.0 * I + 1e-5) / (U + 1e-5);
    }
    for (int off = 32; off > 0; off >>= 1) d += __shfl_down(d, off);
    if (t == 0) out[0] = (float)(1.0 - d / (double)BATCH);
}

// ---------------------------------------------------------------------------
extern "C" void kernel_launch(void* const* d_in, const int* in_sizes, int n_in,
                              void* d_out, int out_size, void* d_ws, size_t ws_size,
                              hipStream_t stream) {
    const float* logits = (const float*)d_in[0];
    const float* target = (const float*)d_in[1];
    const float* eps    = (const float*)d_in[2];
    float* out = (float*)d_out;

    char* ws = (char*)d_ws;
    const size_t h1B = (size_t)BATCH * NB1 * 4;            // 128 KB
    const size_t hAB = (size_t)BATCH * NBA * 4;            // 256 KB
    const size_t hBB = (size_t)BATCH * NBB * 4;            // 256 KB
    uint32_t* hist1 = (uint32_t*)ws;
    uint32_t* histA = (uint32_t*)(ws + h1B);
    uint32_t* histB = (uint32_t*)(ws + h1B + hAB);
    State* st = (State*)(ws + h1B + hAB + hBB);
    const size_t baseNeed = h1B + hAB + hBB + sizeof(State);

    size_t off = ((baseNeed + 255) / 256) * 256;
    uint2* fgList = (uint2*)(ws + off);                    // 32 MB
    off += (size_t)BATCH * FGCAP * sizeof(uint2);
    uint2* cand = (uint2*)(ws + off);                      // 32 MB
    off += (size_t)BATCH * CAP * sizeof(uint2);
    uint2* cand2 = (uint2*)(ws + off);                     // 8 MB
    off += (size_t)BATCH * CAP2 * sizeof(uint2);

    // Zero histograms + state each call (graph-capture safe).
    hipMemsetAsync(ws, 0, baseNeed, stream);

    dim3 grid(NPIX / PXB, BATCH);   // 64 x 32 = 2048 blocks
    k_pass1 <<<grid, 256, 0, stream>>>(logits, target, eps, fgList, hist1, st);
    k_scan1 <<<BATCH, 256, 0, stream>>>(hist1, st);
    k_sums  <<<dim3(32, BATCH), 256, 0, stream>>>(fgList, st, cand, histA);
    k_scanA <<<BATCH, 256, 0, stream>>>(histA, st);
    k_histB <<<dim3(4, BATCH), 256, 0, stream>>>(st, cand, histB, cand2);
    k_scanB <<<BATCH, 256, 0, stream>>>(st, histB, cand2);
    k_finalize<<<1, 64, 0, stream>>>(st, out);
}

// Round 9
// 87.644 us; speedup vs baseline: 1.0671x; 1.0671x over previous
//
#include <hip/hip_runtime.h>
#include <cstdint>
#include <math.h>

#define BATCH 32
#define NPIX (512*512)        // 262144 pixels per batch
#define NB1 1024              // level-1 bins: tp bits [31:22]
#define NCOPY 4               // LDS sub-histogram copies
#define NBA 2048              // select level A: tp bits [21:11]
#define NBB 2048              // select level B: tp bits [10:0]
#define PXB 4096              // pixels per block (256 thr * 16 px)
#define CAP 131072            // candidate capacity per batch (16 MB total, 4B each)
#define CAP2 32768            // binA-candidate capacity per batch (4 MB total)
#define CNTSTRIDE 32          // one cache line (128B) per batch counter

typedef float vfloat4 __attribute__((ext_vector_type(4)));

struct State {
    int      pfx1[BATCH];            // selected 10-bit prefix (-1 if no fg)
    uint32_t krem[BATCH];            // rank within pfx1 bin (1-based)
    int      binA[BATCH];            // selected level-A bin
    uint32_t remA[BATCH];            // rank within binA (1-based)
    uint32_t candcnt[BATCH*CNTSTRIDE];  // candidate count, line-padded
    uint32_t cnt2   [BATCH*CNTSTRIDE];  // binA-candidate count, line-padded
    double   I_low[BATCH];           // sum tp    over surely-kept fg (p~=tp)
    double   U_low[BATCH];           // sum tp^2+1 over same
    double   S_bg [BATCH];           // sum p^2 over background (exact p)
    double   I_cnd[BATCH];           // sum tp    over kept candidates
    double   U_cnd[BATCH];           // sum tp^2+1 over kept candidates
};

// ---------------------------------------------------------------------------
// k1: pure stream + hist. Read 128 MB, softmax, write tpv (fg->tp, bg->-p)
// with NON-TEMPORAL stores (keep inputs L3-resident), LDS count histogram.
// ---------------------------------------------------------------------------
__global__ __launch_bounds__(256)
void k_pass1(const float* __restrict__ logits,
             const float* __restrict__ target,
             const float* __restrict__ eps,
             float* __restrict__ tpv,
             uint32_t* __restrict__ hist1)
{
    __shared__ uint32_t lh[NB1 * NCOPY];   // 16 KB
    const int tid = threadIdx.x;
    const int copy = tid & (NCOPY - 1);
    for (int i = tid; i < NB1 * NCOPY; i += 256) lh[i] = 0;
    __syncthreads();

    const int b = blockIdx.y;
    const size_t nbase = (size_t)b * NPIX;
    const size_t lbase = (size_t)b * 2 * NPIX;
    const int base = blockIdx.x * PXB;

    float4 L0[4], L1[4], T4[4], E4[4];
#pragma unroll
    for (int it = 0; it < 4; ++it) {
        const int i0 = base + (it * 256 + tid) * 4;
        L0[it] = *(const float4*)(logits + lbase + i0);
        L1[it] = *(const float4*)(logits + lbase + NPIX + i0);
        T4[it] = *(const float4*)(target + nbase + i0);
        E4[it] = *(const float4*)(eps    + nbase + i0);
    }

#pragma unroll
    for (int it = 0; it < 4; ++it) {
        const int i0 = base + (it * 256 + tid) * 4;
        float a0[4] = {L0[it].x, L0[it].y, L0[it].z, L0[it].w};
        float a1[4] = {L1[it].x, L1[it].y, L1[it].z, L1[it].w};
        float tv[4] = {T4[it].x, T4[it].y, T4[it].z, T4[it].w};
        float ev[4] = {E4[it].x, E4[it].y, E4[it].z, E4[it].w};
        vfloat4 vv;
#pragma unroll
        for (int j = 0; j < 4; ++j) {
            float m  = fmaxf(a0[j], a1[j]);
            float e0 = expf(a0[j] - m);
            float e1 = expf(a1[j] - m);
            float p  = e1 / (e0 + e1);
            float tp = p * (tv[j] + ev[j]);
            bool fg  = (tv[j] == 1.0f);
            if (fg) {
                atomicAdd(&lh[(__float_as_uint(tp) >> 22) * NCOPY + copy], 1u);
                vv[j] = tp;              // positive
            } else {
                vv[j] = -p;              // sign bit marks background
            }
        }
        __builtin_nontemporal_store(vv, (vfloat4*)(tpv + nbase + i0));
    }

    __syncthreads();
    uint32_t* hb = hist1 + (size_t)b * NB1;
    for (int bin = tid; bin < NB1; bin += 256) {
        uint32_t v = lh[bin*NCOPY+0] + lh[bin*NCOPY+1] + lh[bin*NCOPY+2] + lh[bin*NCOPY+3];
        if (v) atomicAdd(hb + bin, v);
    }
}

// ---------------------------------------------------------------------------
// Scan level-1: pick 10-bit prefix containing rank k = max(1, n_fg/2).
// ---------------------------------------------------------------------------
__global__ __launch_bounds__(256)
void k_scan1(const uint32_t* __restrict__ hist1, State* st)
{
    const int b = blockIdx.x;
    const int t = threadIdx.x;
    const uint32_t* h = hist1 + (size_t)b * NB1;
    __shared__ uint32_t part[256];
    __shared__ int sBin; __shared__ uint32_t sRem;
    if (t == 0) { sBin = 0; sRem = 1; }

    const int g = NB1 / 256;   // 4
    uint32_t s = 0;
    for (int j = 0; j < g; ++j) s += h[t * g + j];
    part[t] = s;
    __syncthreads();
    for (int off = 1; off < 256; off <<= 1) {
        uint32_t v = (t >= off) ? part[t - off] : 0u;
        __syncthreads();
        part[t] += v;
        __syncthreads();
    }
    uint32_t incl = part[t], excl = incl - s;
    uint32_t total = part[255];
    if (total == 0) {
        if (t == 0) { st->pfx1[b] = -1; st->krem[b] = 0; }
        return;
    }
    uint32_t k = total / 2;
    if (k == 0) k = 1;

    if (excl < k && k <= incl) {
        uint32_t run = excl;
        for (int j = 0; j < g; ++j) {
            uint32_t c = h[t * g + j];
            if (run < k && k <= run + c) { sBin = t * g + j; sRem = k - run; break; }
            run += c;
        }
    }
    __syncthreads();
    if (t == 0) { st->pfx1[b] = sBin; st->krem[b] = sRem; }
}

// ---------------------------------------------------------------------------
// k2: single 32 MB pass over tpv. bg -> S_bg; fg bin<pfx1 -> I/U_low;
// bin==pfx1 -> candidate (4B tp bits): wave-aggregated append + LDS histA.
// ---------------------------------------------------------------------------
__global__ __launch_bounds__(256)
void k_pass2(const float* __restrict__ tpv,
             State* st, uint32_t* __restrict__ cand,
             uint32_t* __restrict__ histA)
{
    const int b = blockIdx.y;
    const int tid = threadIdx.x;
    const int lane = tid & 63;
    const int pfx = st->pfx1[b];
    const size_t nbase = (size_t)b * NPIX;
    const int base = blockIdx.x * PXB;
    uint32_t* cb = cand + (size_t)b * CAP;

    __shared__ uint32_t lhA[NBA];          // 8 KB
    for (int i = tid; i < NBA; i += 256) lhA[i] = 0;
    __syncthreads();

    float4 V4[4];
#pragma unroll
    for (int it = 0; it < 4; ++it) {
        const int i0 = base + (it * 256 + tid) * 4;
        V4[it] = *(const float4*)(tpv + nbase + i0);
    }

    uint32_t tpb_[16];
    uint32_t predmask = 0;
    double Il = 0.0, Ul = 0.0, Sbg = 0.0;
#pragma unroll
    for (int it = 0; it < 4; ++it) {
        float vv[4] = {V4[it].x, V4[it].y, V4[it].z, V4[it].w};
#pragma unroll
        for (int j = 0; j < 4; ++j) {
            const int idx = it * 4 + j;
            uint32_t bits = __float_as_uint(vv[j]);
            tpb_[idx] = bits;
            if (bits >> 31) {                       // background: -p
                float p = __uint_as_float(bits & 0x7FFFFFFFu);
                Sbg += (double)p * (double)p;
            } else {                                // foreground: tp
                int bin = (int)(bits >> 22);
                float tp = vv[j];
                if (bin < pfx) {
                    Il += (double)tp;
                    Ul += (double)tp * (double)tp + 1.0;
                } else if (bin == pfx) {
                    predmask |= (1u << idx);
                    atomicAdd(&lhA[(bits >> 11) & (NBA - 1)], 1u);
                }
            }
        }
    }

    // Wave-aggregated append: ONE returning atomic per wave.
    uint32_t c = (uint32_t)__popc(predmask);
    uint32_t inc = c;
#pragma unroll
    for (int off = 1; off < 64; off <<= 1) {
        uint32_t v = __shfl_up(inc, off);
        if (lane >= off) inc += v;
    }
    uint32_t excl = inc - c;
    uint32_t wtotal = __shfl(inc, 63);
    uint32_t basec = 0;
    if (lane == 0 && wtotal) basec = atomicAdd(&st->candcnt[b * CNTSTRIDE], wtotal);
    basec = __shfl(basec, 0);

    uint32_t pos = basec + excl;
#pragma unroll
    for (int idx = 0; idx < 16; ++idx) {
        if ((predmask >> idx) & 1u) {
            if (pos < CAP) cb[pos] = tpb_[idx];
            pos++;
        }
    }

    __syncthreads();
    uint32_t* hA = histA + (size_t)b * NBA;
    for (int i = tid; i < NBA; i += 256) {
        uint32_t v = lhA[i];
        if (v) atomicAdd(hA + i, v);
    }

    __shared__ double sI[256];
    __shared__ double sU[256];
    __shared__ double sB[256];
    sI[tid] = Il; sU[tid] = Ul; sB[tid] = Sbg;
    __syncthreads();
    for (int off = 128; off > 0; off >>= 1) {
        if (tid < off) { sI[tid] += sI[tid+off]; sU[tid] += sU[tid+off]; sB[tid] += sB[tid+off]; }
        __syncthreads();
    }
    if (tid == 0) {
        atomicAdd(&st->I_low[b], sI[0]);
        atomicAdd(&st->U_low[b], sU[0]);
        atomicAdd(&st->S_bg[b],  sB[0]);
    }
}

// ---------------------------------------------------------------------------
#define SELECT_BIN(h, nb, k)                                                  \
    {                                                                         \
        const int g = (nb) / 256;                                             \
        uint32_t s = 0;                                                       \
        for (int j = 0; j < g; ++j) s += (h)[t * g + j];                      \
        part[t] = s;                                                          \
        __syncthreads();                                                      \
        for (int off = 1; off < 256; off <<= 1) {                             \
            uint32_t v = (t >= off) ? part[t - off] : 0u;                     \
            __syncthreads();                                                  \
            part[t] += v;                                                     \
            __syncthreads();                                                  \
        }                                                                     \
        uint32_t incl = part[t], excl = incl - s;                             \
        if (excl < (k) && (k) <= incl) {                                      \
            uint32_t run = excl;                                              \
            for (int j = 0; j < g; ++j) {                                     \
                uint32_t c = (h)[t * g + j];                                  \
                if (run < (k) && (k) <= run + c) {                            \
                    sBin = t * g + j;                                         \
                    sRem = (k) - run;                                         \
                    break;                                                    \
                }                                                             \
                run += c;                                                     \
            }                                                                 \
        }                                                                     \
        __syncthreads();                                                      \
    }

// Scan level-A histogram -> binA, remA.
__global__ __launch_bounds__(256)
void k_scanA(const uint32_t* __restrict__ histA, State* st)
{
    const int b = blockIdx.x;
    const int t = threadIdx.x;
    if (st->pfx1[b] < 0) return;
    const uint32_t* h = histA + (size_t)b * NBA;
    const uint32_t k = st->krem[b];
    __shared__ uint32_t part[256];
    __shared__ int sBin; __shared__ uint32_t sRem;
    if (t == 0) { sBin = 0; sRem = 1; }
    __syncthreads();
    SELECT_BIN(h, NBA, k);
    if (t == 0) { st->binA[b] = sBin; st->remA[b] = sRem; }
}

// ---------------------------------------------------------------------------
// Level-B pass over candidates (parallel): sub<binA -> kept sums; sub==binA ->
// LDS histB + compact into tiny cand2 list.
// ---------------------------------------------------------------------------
__global__ __launch_bounds__(256)
void k_histB(State* st, const uint32_t* __restrict__ cand,
             uint32_t* __restrict__ histB, uint32_t* __restrict__ cand2)
{
    const int b = blockIdx.y;
    const int t = threadIdx.x;
    if (st->pfx1[b] < 0) return;
    const uint32_t binA = (uint32_t)st->binA[b];
    const uint32_t n = min(st->candcnt[b * CNTSTRIDE], (uint32_t)CAP);
    const uint32_t* cb = cand + (size_t)b * CAP;
    uint32_t* c2 = cand2 + (size_t)b * CAP2;

    __shared__ uint32_t lhB[NBB];          // 8 KB
    for (int i = t; i < NBB; i += 256) lhB[i] = 0;
    __syncthreads();

    double I = 0.0, U = 0.0;
    for (uint32_t i = blockIdx.x * 256 + t; i < n; i += gridDim.x * 256) {
        uint32_t bits = cb[i];
        uint32_t sub = (bits >> 11) & (NBA - 1);
        if (sub < binA) {
            float tp = __uint_as_float(bits);
            I += (double)tp;
            U += (double)tp * (double)tp + 1.0;
        } else if (sub == binA) {
            atomicAdd(&lhB[bits & (NBB - 1)], 1u);
            uint32_t pos = atomicAdd(&st->cnt2[b * CNTSTRIDE], 1u);
            if (pos < CAP2) c2[pos] = bits;
        }
    }

    __syncthreads();
    uint32_t* hB = histB + (size_t)b * NBB;
    for (int i = t; i < NBB; i += 256) {
        uint32_t v = lhB[i];
        if (v) atomicAdd(hB + i, v);
    }

    __shared__ double sI[256];
    __shared__ double sU[256];
    sI[t] = I; sU[t] = U;
    __syncthreads();
    for (int off = 128; off > 0; off >>= 1) {
        if (t < off) { sI[t] += sI[t+off]; sU[t] += sU[t+off]; }
        __syncthreads();
    }
    if (t == 0) {
        atomicAdd(&st->I_cnd[b], sI[0]);
        atomicAdd(&st->U_cnd[b], sU[0]);
    }
}

// ---------------------------------------------------------------------------
// Scan level-B histogram -> binB -> thr; sum the tiny cand2 list <= thr.
// ---------------------------------------------------------------------------
__global__ __launch_bounds__(256)
void k_scanB(State* st, const uint32_t* __restrict__ histB,
             const uint32_t* __restrict__ cand2)
{
    const int b = blockIdx.x;
    const int t = threadIdx.x;
    const int pfx = st->pfx1[b];
    if (pfx < 0) return;
    const uint32_t* h = histB + (size_t)b * NBB;
    const uint32_t k = st->remA[b];
    const uint32_t binA = (uint32_t)st->binA[b];
    const uint32_t* c2 = cand2 + (size_t)b * CAP2;
    const uint32_t n2 = min(st->cnt2[b * CNTSTRIDE], (uint32_t)CAP2);

    __shared__ uint32_t part[256];
    __shared__ int sBin; __shared__ uint32_t sRem;
    if (t == 0) { sBin = 0; sRem = 1; }
    __syncthreads();
    SELECT_BIN(h, NBB, k);
    const uint32_t binB = (uint32_t)sBin;
    const uint32_t thr_bits = ((uint32_t)pfx << 22) | (binA << 11) | binB;

    double I = 0.0, U = 0.0;
    for (uint32_t i = t; i < n2; i += 256) {
        uint32_t bits = c2[i];
        if (bits <= thr_bits) {
            float tp = __uint_as_float(bits);
            I += (double)tp;
            U += (double)tp * (double)tp + 1.0;
        }
    }
    __shared__ double sI[256];
    __shared__ double sU[256];
    sI[t] = I; sU[t] = U;
    __syncthreads();
    for (int off = 128; off > 0; off >>= 1) {
        if (t < off) { sI[t] += sI[t+off]; sU[t] += sU[t+off]; }
        __syncthreads();
    }
    if (t == 0) {
        atomicAdd(&st->I_cnd[b], sI[0]);
        atomicAdd(&st->U_cnd[b], sU[0]);
    }
}

__global__ void k_finalize(const State* __restrict__ st, float* __restrict__ out)
{
    const int t = threadIdx.x;
    double d = 0.0;
    if (t < BATCH) {
        double I = st->I_low[t] + st->I_cnd[t];
        double U = st->U_low[t] + st->U_cnd[t] + st->S_bg[t];
        d = (2.0 * I + 1e-5) / (U + 1e-5);
    }
    for (int off = 32; off > 0; off >>= 1) d += __shfl_down(d, off);
    if (t == 0) out[0] = (float)(1.0 - d / (double)BATCH);
}

// ---------------------------------------------------------------------------
extern "C" void kernel_launch(void* const* d_in, const int* in_sizes, int n_in,
                              void* d_out, int out_size, void* d_ws, size_t ws_size,
                              hipStream_t stream) {
    const float* logits = (const float*)d_in[0];
    const float* target = (const float*)d_in[1];
    const float* eps    = (const float*)d_in[2];
    float* out = (float*)d_out;

    char* ws = (char*)d_ws;
    const size_t h1B = (size_t)BATCH * NB1 * 4;            // 128 KB
    const size_t hAB = (size_t)BATCH * NBA * 4;            // 256 KB
    const size_t hBB = (size_t)BATCH * NBB * 4;            // 256 KB
    uint32_t* hist1 = (uint32_t*)ws;
    uint32_t* histA = (uint32_t*)(ws + h1B);
    uint32_t* histB = (uint32_t*)(ws + h1B + hAB);
    State* st = (State*)(ws + h1B + hAB + hBB);
    const size_t baseNeed = h1B + hAB + hBB + sizeof(State);

    size_t off = ((baseNeed + 255) / 256) * 256;
    uint32_t* cand = (uint32_t*)(ws + off);                // 16 MB
    off += (size_t)BATCH * CAP * sizeof(uint32_t);
    uint32_t* cand2 = (uint32_t*)(ws + off);               // 4 MB
    off += (size_t)BATCH * CAP2 * sizeof(uint32_t);
    float* tpv = (float*)(ws + off);                       // 32 MB
    off += (size_t)BATCH * NPIX * sizeof(float);

    // Zero histograms + state each call (graph-capture safe).
    hipMemsetAsync(ws, 0, baseNeed, stream);

    dim3 grid(NPIX / PXB, BATCH);   // 64 x 32 = 2048 blocks
    k_pass1 <<<grid, 256, 0, stream>>>(logits, target, eps, tpv, hist1);
    k_scan1 <<<BATCH, 256, 0, stream>>>(hist1, st);
    k_pass2 <<<grid, 256, 0, stream>>>(tpv, st, cand, histA);
    k_scanA <<<BATCH, 256, 0, stream>>>(histA, st);
    k_histB <<<dim3(4, BATCH), 256, 0, stream>>>(st, cand, histB, cand2);
    k_scanB <<<BATCH, 256, 0, stream>>>(st, histB, cand2);
    k_finalize<<<1, 64, 0, stream>>>(st, out);
}

// Round 10
// 82.831 us; speedup vs baseline: 1.1291x; 1.0581x over previous
//
#include <hip/hip_runtime.h>
#include <cstdint>
#include <math.h>

#define BATCH 32
#define NPIX (512*512)        // 262144 pixels per batch
#define NB1 1024              // level-1 bins: tp bits [31:22]
#define NCOPY 4               // LDS sub-histogram copies (k_hist1 only)
#define NBA 2048              // select level A: tp bits [21:11]
#define NBB 2048              // select level B: tp bits [10:0]
#define PXB 4096              // pixels per block (256 thr * 16 px)
#define FGCAP 131072          // fg-list capacity per batch (16 MB total, 4B)
#define CAP 32768             // candidate capacity per batch (4 MB total)
#define CAP2 8192             // binA-candidate capacity per batch (1 MB total)
#define CNTSTRIDE 32          // one cache line (128B) per batch counter

struct State {
    int      pfx1[BATCH];            // selected 10-bit prefix (-1 if no fg)
    uint32_t krem[BATCH];            // rank within pfx1 bin (1-based)
    int      binA[BATCH];            // selected level-A bin
    uint32_t remA[BATCH];            // rank within binA (1-based)
    uint32_t fgcnt  [BATCH*CNTSTRIDE];
    uint32_t candcnt[BATCH*CNTSTRIDE];
    uint32_t cnt2   [BATCH*CNTSTRIDE];
    double   I_low[BATCH];           // sum tp     over surely-kept fg
    double   U_low[BATCH];           // sum tp^2+1 over same
    double   S_bg [BATCH];           // sum p^2 over background
    double   I_cnd[BATCH];           // sum tp     over kept candidates
    double   U_cnd[BATCH];           // sum tp^2+1 over kept candidates
};

// ---------------------------------------------------------------------------
// k1: PURE STREAM. Read 128 MB, softmax; bg -> S_bg inline; fg -> tp bits
// compacted per-wave into LDS (register running count + ballot, NO LDS
// atomics), flushed with ONE returning global atomic per wave.
// ---------------------------------------------------------------------------
__global__ __launch_bounds__(256)
void k_stream(const float* __restrict__ logits,
              const float* __restrict__ target,
              const float* __restrict__ eps,
              uint32_t* __restrict__ fgList,
              State* st)
{
    __shared__ uint32_t stage[4][1024];   // per-wave staging, 16 KB
    const int tid  = threadIdx.x;
    const int wid  = tid >> 6;
    const int lane = tid & 63;
    const int b    = blockIdx.y;
    const size_t nbase = (size_t)b * NPIX;
    const size_t lbase = (size_t)b * 2 * NPIX;
    const int base = blockIdx.x * PXB;
    const unsigned long long lmask = (1ULL << lane) - 1ULL;

    uint32_t wcount = 0;
    double Sbg = 0.0;

#pragma unroll
    for (int it = 0; it < 4; ++it) {
        const int i0 = base + (it * 256 + tid) * 4;
        float4 l0 = *(const float4*)(logits + lbase + i0);
        float4 l1 = *(const float4*)(logits + lbase + NPIX + i0);
        float4 tt = *(const float4*)(target + nbase + i0);
        float4 ee = *(const float4*)(eps    + nbase + i0);
        float a0[4] = {l0.x, l0.y, l0.z, l0.w};
        float a1[4] = {l1.x, l1.y, l1.z, l1.w};
        float tv[4] = {tt.x, tt.y, tt.z, tt.w};
        float ev[4] = {ee.x, ee.y, ee.z, ee.w};
#pragma unroll
        for (int j = 0; j < 4; ++j) {
            float m  = fmaxf(a0[j], a1[j]);
            float e0 = expf(a0[j] - m);
            float e1 = expf(a1[j] - m);
            float p  = e1 / (e0 + e1);
            float tp = p * (tv[j] + ev[j]);
            bool fg  = (tv[j] == 1.0f);
            unsigned long long msk = __ballot(fg);
            uint32_t pos = wcount + (uint32_t)__popcll(msk & lmask);
            if (fg) stage[wid][pos] = __float_as_uint(tp);
            else    Sbg += (double)p * (double)p;
            wcount += (uint32_t)__popcll(msk);
        }
    }

    // Per-wave flush: one returning atomic, then coalesced copy.
    uint32_t basec = 0;
    if (lane == 0 && wcount) basec = atomicAdd(&st->fgcnt[b * CNTSTRIDE], wcount);
    basec = __shfl(basec, 0);
    uint32_t* fgb = fgList + (size_t)b * FGCAP;
    for (uint32_t i = lane; i < wcount; i += 64) {
        uint32_t pos = basec + i;
        if (pos < FGCAP) fgb[pos] = stage[wid][i];
    }

    __shared__ double sB[256];
    sB[tid] = Sbg;
    __syncthreads();
    for (int off = 128; off > 0; off >>= 1) {
        if (tid < off) sB[tid] += sB[tid + off];
        __syncthreads();
    }
    if (tid == 0) atomicAdd(&st->S_bg[b], sB[0]);
}

// ---------------------------------------------------------------------------
// k2: level-1 histogram FROM the fg-list (L2/L3-hot). Its cost is now
// visible in isolation.
// ---------------------------------------------------------------------------
__global__ __launch_bounds__(256)
void k_hist1(const uint32_t* __restrict__ fgList,
             const State* __restrict__ st,
             uint32_t* __restrict__ hist1)
{
    __shared__ uint32_t lh[NB1 * NCOPY];   // 16 KB
    const int tid = threadIdx.x;
    const int copy = tid & (NCOPY - 1);
    for (int i = tid; i < NB1 * NCOPY; i += 256) lh[i] = 0;
    __syncthreads();

    const int b = blockIdx.y;
    const uint32_t n = min(st->fgcnt[b * CNTSTRIDE], (uint32_t)FGCAP);
    const uint32_t* fgb = fgList + (size_t)b * FGCAP;
    for (uint32_t i = blockIdx.x * 256 + tid; i < n; i += gridDim.x * 256)
        atomicAdd(&lh[(fgb[i] >> 22) * NCOPY + copy], 1u);

    __syncthreads();
    uint32_t* hb = hist1 + (size_t)b * NB1;
    for (int bin = tid; bin < NB1; bin += 256) {
        uint32_t v = lh[bin*NCOPY+0] + lh[bin*NCOPY+1] + lh[bin*NCOPY+2] + lh[bin*NCOPY+3];
        if (v) atomicAdd(hb + bin, v);
    }
}

// ---------------------------------------------------------------------------
// Scan level-1: pick 10-bit prefix containing rank k = max(1, n_fg/2).
// ---------------------------------------------------------------------------
__global__ __launch_bounds__(256)
void k_scan1(const uint32_t* __restrict__ hist1, State* st)
{
    const int b = blockIdx.x;
    const int t = threadIdx.x;
    const uint32_t* h = hist1 + (size_t)b * NB1;
    __shared__ uint32_t part[256];
    __shared__ int sBin; __shared__ uint32_t sRem;
    if (t == 0) { sBin = 0; sRem = 1; }

    const int g = NB1 / 256;   // 4
    uint32_t s = 0;
    for (int j = 0; j < g; ++j) s += h[t * g + j];
    part[t] = s;
    __syncthreads();
    for (int off = 1; off < 256; off <<= 1) {
        uint32_t v = (t >= off) ? part[t - off] : 0u;
        __syncthreads();
        part[t] += v;
        __syncthreads();
    }
    uint32_t incl = part[t], excl = incl - s;
    uint32_t total = part[255];
    if (total == 0) {
        if (t == 0) { st->pfx1[b] = -1; st->krem[b] = 0; }
        return;
    }
    uint32_t k = total / 2;
    if (k == 0) k = 1;

    if (excl < k && k <= incl) {
        uint32_t run = excl;
        for (int j = 0; j < g; ++j) {
            uint32_t c = h[t * g + j];
            if (run < k && k <= run + c) { sBin = t * g + j; sRem = k - run; break; }
            run += c;
        }
    }
    __syncthreads();
    if (t == 0) { st->pfx1[b] = sBin; st->krem[b] = sRem; }
}

// ---------------------------------------------------------------------------
// k4: pass over fg-list. bin<pfx1 -> I/U_low; bin==pfx1 -> LDS histA +
// per-wave staged candidate append (no per-iteration returning atomics).
// ---------------------------------------------------------------------------
__global__ __launch_bounds__(256)
void k_sums(const uint32_t* __restrict__ fgList,
            State* st, uint32_t* __restrict__ cand,
            uint32_t* __restrict__ histA)
{
    __shared__ uint32_t lhA[NBA];          // 8 KB
    __shared__ uint32_t cstage[4][1312];   // per-wave candidate staging, 21 KB
    const int tid = threadIdx.x;
    const int wid = tid >> 6;
    const int lane = tid & 63;
    const unsigned long long lmask = (1ULL << lane) - 1ULL;
    for (int i = tid; i < NBA; i += 256) lhA[i] = 0;
    __syncthreads();

    const int b = blockIdx.y;
    const int pfx = st->pfx1[b];
    if (pfx < 0) return;
    const uint32_t n = min(st->fgcnt[b * CNTSTRIDE], (uint32_t)FGCAP);
    const uint32_t* fgb = fgList + (size_t)b * FGCAP;
    uint32_t* cb = cand + (size_t)b * CAP;

    uint32_t wcount = 0;
    double Il = 0.0, Ul = 0.0;
    for (uint32_t i = blockIdx.x * 256 + tid; i < n; i += gridDim.x * 256) {
        uint32_t bits = fgb[i];
        int bin = (int)(bits >> 22);
        bool isc = (bin == pfx);
        if (bin < pfx) {
            float tp = __uint_as_float(bits);
            Il += (double)tp;
            Ul += (double)tp * (double)tp + 1.0;
        } else if (isc) {
            atomicAdd(&lhA[(bits >> 11) & (NBA - 1)], 1u);
        }
        unsigned long long msk = __ballot(isc);
        uint32_t pos = wcount + (uint32_t)__popcll(msk & lmask);
        if (isc && pos < 1312) cstage[wid][pos] = bits;
        wcount += (uint32_t)__popcll(msk);
    }
    if (wcount > 1312) wcount = 1312;

    uint32_t basec = 0;
    if (lane == 0 && wcount) basec = atomicAdd(&st->candcnt[b * CNTSTRIDE], wcount);
    basec = __shfl(basec, 0);
    for (uint32_t i = lane; i < wcount; i += 64) {
        uint32_t pos = basec + i;
        if (pos < CAP) cb[pos] = cstage[wid][i];
    }

    __syncthreads();
    uint32_t* hA = histA + (size_t)b * NBA;
    for (int i = tid; i < NBA; i += 256) {
        uint32_t v = lhA[i];
        if (v) atomicAdd(hA + i, v);
    }

    __shared__ double sI[256];
    __shared__ double sU[256];
    sI[tid] = Il; sU[tid] = Ul;
    __syncthreads();
    for (int off = 128; off > 0; off >>= 1) {
        if (tid < off) { sI[tid] += sI[tid+off]; sU[tid] += sU[tid+off]; }
        __syncthreads();
    }
    if (tid == 0) {
        atomicAdd(&st->I_low[b], sI[0]);
        atomicAdd(&st->U_low[b], sU[0]);
    }
}

// ---------------------------------------------------------------------------
#define SELECT_BIN(h, nb, k)                                                  \
    {                                                                         \
        const int g = (nb) / 256;                                             \
        uint32_t s = 0;                                                       \
        for (int j = 0; j < g; ++j) s += (h)[t * g + j];                      \
        part[t] = s;                                                          \
        __syncthreads();                                                      \
        for (int off = 1; off < 256; off <<= 1) {                             \
            uint32_t v = (t >= off) ? part[t - off] : 0u;                     \
            __syncthreads();                                                  \
            part[t] += v;                                                     \
            __syncthreads();                                                  \
        }                                                                     \
        uint32_t incl = part[t], excl = incl - s;                             \
        if (excl < (k) && (k) <= incl) {                                      \
            uint32_t run = excl;                                              \
            for (int j = 0; j < g; ++j) {                                     \
                uint32_t c = (h)[t * g + j];                                  \
                if (run < (k) && (k) <= run + c) {                            \
                    sBin = t * g + j;                                         \
                    sRem = (k) - run;                                         \
                    break;                                                    \
                }                                                             \
                run += c;                                                     \
            }                                                                 \
        }                                                                     \
        __syncthreads();                                                      \
    }

__global__ __launch_bounds__(256)
void k_scanA(const uint32_t* __restrict__ histA, State* st)
{
    const int b = blockIdx.x;
    const int t = threadIdx.x;
    if (st->pfx1[b] < 0) return;
    const uint32_t* h = histA + (size_t)b * NBA;
    const uint32_t k = st->krem[b];
    __shared__ uint32_t part[256];
    __shared__ int sBin; __shared__ uint32_t sRem;
    if (t == 0) { sBin = 0; sRem = 1; }
    __syncthreads();
    SELECT_BIN(h, NBA, k);
    if (t == 0) { st->binA[b] = sBin; st->remA[b] = sRem; }
}

// ---------------------------------------------------------------------------
// Level-B pass over candidates: sub<binA -> kept sums; sub==binA -> LDS histB
// + compact into tiny cand2 list.
// ---------------------------------------------------------------------------
__global__ __launch_bounds__(256)
void k_histB(State* st, const uint32_t* __restrict__ cand,
             uint32_t* __restrict__ histB, uint32_t* __restrict__ cand2)
{
    const int b = blockIdx.y;
    const int t = threadIdx.x;
    if (st->pfx1[b] < 0) return;
    const uint32_t binA = (uint32_t)st->binA[b];
    const uint32_t n = min(st->candcnt[b * CNTSTRIDE], (uint32_t)CAP);
    const uint32_t* cb = cand + (size_t)b * CAP;
    uint32_t* c2 = cand2 + (size_t)b * CAP2;

    __shared__ uint32_t lhB[NBB];          // 8 KB
    for (int i = t; i < NBB; i += 256) lhB[i] = 0;
    __syncthreads();

    double I = 0.0, U = 0.0;
    for (uint32_t i = blockIdx.x * 256 + t; i < n; i += gridDim.x * 256) {
        uint32_t bits = cb[i];
        uint32_t sub = (bits >> 11) & (NBA - 1);
        if (sub < binA) {
            float tp = __uint_as_float(bits);
            I += (double)tp;
            U += (double)tp * (double)tp + 1.0;
        } else if (sub == binA) {
            atomicAdd(&lhB[bits & (NBB - 1)], 1u);
            uint32_t pos = atomicAdd(&st->cnt2[b * CNTSTRIDE], 1u);
            if (pos < CAP2) c2[pos] = bits;
        }
    }

    __syncthreads();
    uint32_t* hB = histB + (size_t)b * NBB;
    for (int i = t; i < NBB; i += 256) {
        uint32_t v = lhB[i];
        if (v) atomicAdd(hB + i, v);
    }

    __shared__ double sI[256];
    __shared__ double sU[256];
    sI[t] = I; sU[t] = U;
    __syncthreads();
    for (int off = 128; off > 0; off >>= 1) {
        if (t < off) { sI[t] += sI[t+off]; sU[t] += sU[t+off]; }
        __syncthreads();
    }
    if (t == 0) {
        atomicAdd(&st->I_cnd[b], sI[0]);
        atomicAdd(&st->U_cnd[b], sU[0]);
    }
}

// ---------------------------------------------------------------------------
__global__ __launch_bounds__(256)
void k_scanB(State* st, const uint32_t* __restrict__ histB,
             const uint32_t* __restrict__ cand2)
{
    const int b = blockIdx.x;
    const int t = threadIdx.x;
    const int pfx = st->pfx1[b];
    if (pfx < 0) return;
    const uint32_t* h = histB + (size_t)b * NBB;
    const uint32_t k = st->remA[b];
    const uint32_t binA = (uint32_t)st->binA[b];
    const uint32_t* c2 = cand2 + (size_t)b * CAP2;
    const uint32_t n2 = min(st->cnt2[b * CNTSTRIDE], (uint32_t)CAP2);

    __shared__ uint32_t part[256];
    __shared__ int sBin; __shared__ uint32_t sRem;
    if (t == 0) { sBin = 0; sRem = 1; }
    __syncthreads();
    SELECT_BIN(h, NBB, k);
    const uint32_t binB = (uint32_t)sBin;
    const uint32_t thr_bits = ((uint32_t)pfx << 22) | (binA << 11) | binB;

    double I = 0.0, U = 0.0;
    for (uint32_t i = t; i < n2; i += 256) {
        uint32_t bits = c2[i];
        if (bits <= thr_bits) {
            float tp = __uint_as_float(bits);
            I += (double)tp;
            U += (double)tp * (double)tp + 1.0;
        }
    }
    __shared__ double sI[256];
    __shared__ double sU[256];
    sI[t] = I; sU[t] = U;
    __syncthreads();
    for (int off = 128; off > 0; off >>= 1) {
        if (t < off) { sI[t] += sI[t+off]; sU[t] += sU[t+off]; }
        __syncthreads();
    }
    if (t == 0) {
        atomicAdd(&st->I_cnd[b], sI[0]);
        atomicAdd(&st->U_cnd[b], sU[0]);
    }
}

__global__ void k_finalize(const State* __restrict__ st, float* __restrict__ out)
{
    const int t = threadIdx.x;
    double d = 0.0;
    if (t < BATCH) {
        double I = st->I_low[t] + st->I_cnd[t];
        double U = st->U_low[t] + st->U_cnd[t] + st->S_bg[t];
        d = (2.0 * I + 1e-5) / (U + 1e-5);
    }
    for (int off = 32; off > 0; off >>= 1) d += __shfl_down(d, off);
    if (t == 0) out[0] = (float)(1.0 - d / (double)BATCH);
}

// ---------------------------------------------------------------------------
extern "C" void kernel_launch(void* const* d_in, const int* in_sizes, int n_in,
                              void* d_out, int out_size, void* d_ws, size_t ws_size,
                              hipStream_t stream) {
    const float* logits = (const float*)d_in[0];
    const float* target = (const float*)d_in[1];
    const float* eps    = (const float*)d_in[2];
    float* out = (float*)d_out;

    char* ws = (char*)d_ws;
    const size_t h1B = (size_t)BATCH * NB1 * 4;            // 128 KB
    const size_t hAB = (size_t)BATCH * NBA * 4;            // 256 KB
    const size_t hBB = (size_t)BATCH * NBB * 4;            // 256 KB
    uint32_t* hist1 = (uint32_t*)ws;
    uint32_t* histA = (uint32_t*)(ws + h1B);
    uint32_t* histB = (uint32_t*)(ws + h1B + hAB);
    State* st = (State*)(ws + h1B + hAB + hBB);
    const size_t baseNeed = h1B + hAB + hBB + sizeof(State);

    size_t off = ((baseNeed + 255) / 256) * 256;
    uint32_t* fgList = (uint32_t*)(ws + off);              // 16 MB
    off += (size_t)BATCH * FGCAP * sizeof(uint32_t);
    uint32_t* cand = (uint32_t*)(ws + off);                // 4 MB
    off += (size_t)BATCH * CAP * sizeof(uint32_t);
    uint32_t* cand2 = (uint32_t*)(ws + off);               // 1 MB
    off += (size_t)BATCH * CAP2 * sizeof(uint32_t);

    // Zero histograms + state each call (graph-capture safe).
    hipMemsetAsync(ws, 0, baseNeed, stream);

    dim3 grid(NPIX / PXB, BATCH);   // 64 x 32 = 2048 blocks
    k_stream<<<grid, 256, 0, stream>>>(logits, target, eps, fgList, st);
    k_hist1 <<<dim3(16, BATCH), 256, 0, stream>>>(fgList, st, hist1);
    k_scan1 <<<BATCH, 256, 0, stream>>>(hist1, st);
    k_sums  <<<dim3(16, BATCH), 256, 0, stream>>>(fgList, st, cand, histA);
    k_scanA <<<BATCH, 256, 0, stream>>>(histA, st);
    k_histB <<<dim3(4, BATCH), 256, 0, stream>>>(st, cand, histB, cand2);
    k_scanB <<<BATCH, 256, 0, stream>>>(st, histB, cand2);
    k_finalize<<<1, 64, 0, stream>>>(st, out);
}